// Round 3
// baseline (218.225 us; speedup 1.0000x reference)
//
#include <hip/hip_runtime.h>
#include <math.h>

#define NB   16     // batch
#define IMG  128    // input image side
#define NANG 300
#define NDET 300
#define RE   4      // emission blur radius  (sigma = 1/sqrt(ln2))
#define RA   8      // attenuation blur radius (sigma = 2/sqrt(ln2))
#define WE   (IMG + 2*RE)   // 136 ; hE col xi <-> canvas x = xi+82 ; E support x in [82,218)
#define WA   (IMG + 2*RA)   // 144 ; hA col xi <-> canvas x = xi+78 ; A support x in [78,222)
#define WB   148            // packed canvas box: x,y in [76,224)

typedef float v2f __attribute__((ext_vector_type(2)));

// Gaussian taps: sigma_img -> 2^(-d^2/2); sigma_att -> 2^(-d^2/8). f64 normalize, f32 cast.
__device__ __constant__ float KE[9] = {
  (float)(0.00390625            / 3.0104144100214136),
  (float)(0.04419417382415922   / 3.0104144100214136),
  (float)(0.25                  / 3.0104144100214136),
  (float)(0.7071067811865476    / 3.0104144100214136),
  (float)(1.0                   / 3.0104144100214136),
  (float)(0.7071067811865476    / 3.0104144100214136),
  (float)(0.25                  / 3.0104144100214136),
  (float)(0.04419417382415922   / 3.0104144100214136),
  (float)(0.00390625            / 3.0104144100214136)
};
__device__ __constant__ float KA[17] = {
  (float)(0.00390625            / 6.019333926786741),
  (float)(0.014328188175072987  / 6.019333926786741),
  (float)(0.04419417382415922   / 6.019333926786741),
  (float)(0.11462550540058389   / 6.019333926786741),
  (float)(0.25                  / 6.019333926786741),
  (float)(0.4585020216023356    / 6.019333926786741),
  (float)(0.7071067811865476    / 6.019333926786741),
  (float)(0.9170040432046712    / 6.019333926786741),
  (float)(1.0                   / 6.019333926786741),
  (float)(0.9170040432046712    / 6.019333926786741),
  (float)(0.7071067811865476    / 6.019333926786741),
  (float)(0.4585020216023356    / 6.019333926786741),
  (float)(0.25                  / 6.019333926786741),
  (float)(0.11462550540058389   / 6.019333926786741),
  (float)(0.04419417382415922   / 6.019333926786741),
  (float)(0.014328188175072987  / 6.019333926786741),
  (float)(0.00390625            / 6.019333926786741)
};

// K1: horizontal blur. hE[y][xi][b], hA[y][xi][b] (b innermost). Image reads coalesced.
__global__ void k_hblur(const float* __restrict__ img, const float* __restrict__ att,
                        float* __restrict__ hE, float* __restrict__ hA) {
  int xi = threadIdx.x;
  int y  = blockIdx.x;
  int b  = blockIdx.y;
  if (blockIdx.z == 0) {
    if (xi >= WE) return;
    const float* src = img + (b * IMG + y) * IMG;
    float acc = 0.f;
#pragma unroll
    for (int d = 0; d < 9; ++d) {
      int col = xi - 2 * RE + d;
      if (col >= 0 && col < IMG) acc = fmaf(KE[d], src[col], acc);
    }
    hE[(y * WE + xi) * NB + b] = acc;
  } else {
    if (xi >= WA) return;
    const float* src = att + (b * IMG + y) * IMG;
    float acc = 0.f;
#pragma unroll
    for (int d = 0; d < 17; ++d) {
      int col = xi - 2 * RA + d;
      if (col >= 0 && col < IMG) acc = fmaf(KA[d], src[col], acc);
    }
    hA[(y * WA + xi) * NB + b] = acc;
  }
}

// K2: vertical blur -> packed canvas over the live box [76,224)^2:
// P[y'][x'][b] = float4( E, 0.01*A, E(x+1), 0.01*A(x+1) ).
__global__ void k_canvas(const float* __restrict__ hE, const float* __restrict__ hA,
                         float4* __restrict__ P) {
  int t  = threadIdx.x;
  int b  = t & 15;
  int xs = t >> 4;
  int xp = blockIdx.x * 16 + xs;        // x' in [0,148)
  int yp = blockIdx.y;                  // y' in [0,148)
  if (xp >= WB) return;

  float E0 = 0.f, E1 = 0.f, A0 = 0.f, A1 = 0.f;
  {
    int xiE = xp - 6;
    bool c0 = (xiE >= 0) & (xiE < WE);
    bool c1 = (xiE + 1 >= 0) & (xiE + 1 < WE);
#pragma unroll
    for (int d = 0; d < 9; ++d) {
      int row = yp - 14 + d;
      if (row >= 0 && row < IMG) {
        const float* base = hE + (row * WE) * NB + b;
        if (c0) E0 = fmaf(KE[d], base[xiE * NB], E0);
        if (c1) E1 = fmaf(KE[d], base[(xiE + 1) * NB], E1);
      }
    }
  }
  {
    int xiA = xp - 2;
    bool c0 = (xiA >= 0) & (xiA < WA);
    bool c1 = (xiA + 1 >= 0) & (xiA + 1 < WA);
#pragma unroll
    for (int d = 0; d < 17; ++d) {
      int row = yp - 18 + d;
      if (row >= 0 && row < IMG) {
        const float* base = hA + (row * WA) * NB + b;
        if (c0) A0 = fmaf(KA[d], base[xiA * NB], A0);
        if (c1) A1 = fmaf(KA[d], base[(xiA + 1) * NB], A1);
      }
    }
  }
  P[(yp * WB + xp) * NB + b] = make_float4(E0, 0.01f * A0, E1, 0.01f * A1);
}

// K3: radon for E and A together. Lanes: b = tid&15 (coalesced 256-B row-pair loads),
// 4 bins/wave. 8x unrolled (16 dwordx4 in flight). Tail samples clamped to the chord
// end 'hi' land on guaranteed-zero canvas -> exact 0 contribution, no divergent tail.
__global__ void k_radon(const float4* __restrict__ P, float* __restrict__ S) {
  int t = threadIdx.x;
  int b  = t & 15;
  int jj = t >> 4;
  int j  = blockIdx.x * 16 + jj;
  int a  = blockIdx.y;
  if (j >= NDET) return;
  float th = (float)a * (float)(3.14159265358979323846 / 299.0);
  float c = cosf(th), s = sinf(th);
  float xj = fmaf((float)j, (float)(2.0 / 299.0), -1.0f);
  // px(i) = pb + s*i ; py(i) = qb + c*i (unit step)
  float pb = fmaf(c,  xj, 1.0f) * 149.5f - 149.5f * s;
  float qb = fmaf(-s, xj, 1.0f) * 149.5f - 149.5f * c;
  const float L = 76.5f, H = 222.5f;
  float lo = 0.f, hi = 299.0f;
  if (s > 1e-6f) {                       // s >= 0 for theta in [0,180]
    float inv = 1.0f / s;
    lo = fmaxf(lo, (L - pb) * inv); hi = fminf(hi, (H - pb) * inv);
  } else if (pb < L || pb > H) { hi = -1.f; }
  if (fabsf(c) > 1e-6f) {
    float inv = 1.0f / c;
    float t0 = (L - qb) * inv, t1 = (H - qb) * inv;
    lo = fmaxf(lo, fminf(t0, t1)); hi = fminf(hi, fmaxf(t0, t1));
  } else if (qb < L || qb > H) { hi = -1.f; }
  int i0 = (int)ceilf(lo);
  int i1 = (int)floorf(hi);

  v2f acc = {0.f, 0.f};
  // byte offset: ((y0-76)*148 + (x0-76))*256 + b*16  -> uniform base + 32-bit voffset
  const char* Pc = (const char*)P;
  int boff = b * 16 - 76 * 149 * 256;

  for (int i = i0; i <= i1; i += 8) {
    float4 r0[8], r1[8];
    float wx[8], wy[8];
#pragma unroll
    for (int u = 0; u < 8; ++u) {
      float fi = fminf((float)(i + u), hi);   // tail -> chord end -> zero canvas
      float px = fmaf(fi, s, pb);
      float py = fmaf(fi, c, qb);
      int x0 = (int)px, y0 = (int)py;         // px,py > 0 -> trunc == floor
      wx[u] = px - (float)x0;
      wy[u] = py - (float)y0;
      int off = (y0 * WB + x0) * 256 + boff;
      r0[u] = *(const float4*)(Pc + off);
      r1[u] = *(const float4*)(Pc + off + WB * 256);
    }
#pragma unroll
    for (int u = 0; u < 8; ++u) {
      v2f lo0 = {r0[u].x, r0[u].y}, hi0 = {r0[u].z, r0[u].w};
      v2f lo1 = {r1[u].x, r1[u].y}, hi1 = {r1[u].z, r1[u].w};
      v2f wx2 = {wx[u], wx[u]};
      v2f wy2 = {wy[u], wy[u]};
      v2f top = lo0 + wx2 * (hi0 - lo0);
      v2f bot = lo1 + wx2 * (hi1 - lo1);
      acc += top + wy2 * (bot - top);
    }
  }
  S[(a * NDET + j) * NB + b] = acc.x * expf(-2.0f * acc.y);  // VOXEL_MM = 2
}

// K4: per-angle 5-tap detector blur (reflect) + scale, write final [b][a][j].
__global__ void k_dblur(const float* __restrict__ S, const float* __restrict__ scale,
                        float* __restrict__ out) {
  int t = threadIdx.x;
  int b  = t & 15;
  int jj = t >> 4;
  int j  = blockIdx.x * 16 + jj;
  int a  = blockIdx.y;
  if (j >= NDET) return;
  float th = (float)a * (float)(3.14159265358979323846 / 299.0);
  float c = cosf(th), s = sinf(th);
  float u = fabsf(c) + fabsf(s);          // bw = 2u
  float u2 = u * u;
  float e1 = exp2f(-2.0f * u2);
  float e2 = exp2f(-8.0f * u2);
  float norm = 1.0f / (1.0f + 2.0f * (e1 + e2));
  float w2c = norm, w1c = e1 * norm, w0c = e2 * norm;
  const float* row = S + a * NDET * NB + b;
  float acc = 0.f;
#pragma unroll
  for (int tt = -2; tt <= 2; ++tt) {
    int jr = j + tt;
    if (jr < 0) jr = -jr;
    if (jr > 299) jr = 598 - jr;
    float w = (tt == 0) ? w2c : ((tt == 1 || tt == -1) ? w1c : w0c);
    acc = fmaf(w, row[jr * NB], acc);
  }
  out[(b * NANG + a) * NDET + j] = acc * scale[b];
}

extern "C" void kernel_launch(void* const* d_in, const int* in_sizes, int n_in,
                              void* d_out, int out_size, void* d_ws, size_t ws_size,
                              hipStream_t stream) {
  const float* img   = (const float*)d_in[0];
  const float* att   = (const float*)d_in[1];
  const float* scale = (const float*)d_in[2];
  float* out = (float*)d_out;
  float* ws  = (float*)d_ws;

  // ws layout (floats): P 148*148*16 float4 (5.61 MB) | S 300*300*16 (5.76 MB) | hE | hA
  float4* P  = (float4*)ws;
  float*  S  = ws + 1401856;
  float*  hE = ws + 2841856;
  float*  hA = ws + 3120384;

  k_hblur <<<dim3(IMG, NB, 2), 192, 0, stream>>>(img, att, hE, hA);
  k_canvas<<<dim3(10, WB),     256, 0, stream>>>(hE, hA, P);
  k_radon <<<dim3(19, NANG),   256, 0, stream>>>(P, S);
  k_dblur <<<dim3(19, NANG),   256, 0, stream>>>(S, scale, out);
}

// Round 4
// 188.108 us; speedup vs baseline: 1.1601x; 1.1601x over previous
//
#include <hip/hip_runtime.h>
#include <math.h>

#define NB   16     // batch
#define IMG  128    // input image side
#define NANG 300
#define NDET 300
#define RE   4      // emission blur radius  (sigma = 1/sqrt(ln2))
#define RA   8      // attenuation blur radius (sigma = 2/sqrt(ln2))
#define WE   (IMG + 2*RE)   // 136 ; hE col xi <-> canvas x = xi+82 ; E support x in [82,218)
#define WA   (IMG + 2*RA)   // 144 ; hA col xi <-> canvas x = xi+78 ; A support x in [78,222)
#define WB   148            // packed canvas box: x,y in [76,224)

typedef float v2f __attribute__((ext_vector_type(2)));

// Gaussian taps: sigma_img -> 2^(-d^2/2); sigma_att -> 2^(-d^2/8). f64 normalize, f32 cast.
__device__ __constant__ float KE[9] = {
  (float)(0.00390625            / 3.0104144100214136),
  (float)(0.04419417382415922   / 3.0104144100214136),
  (float)(0.25                  / 3.0104144100214136),
  (float)(0.7071067811865476    / 3.0104144100214136),
  (float)(1.0                   / 3.0104144100214136),
  (float)(0.7071067811865476    / 3.0104144100214136),
  (float)(0.25                  / 3.0104144100214136),
  (float)(0.04419417382415922   / 3.0104144100214136),
  (float)(0.00390625            / 3.0104144100214136)
};
__device__ __constant__ float KA[17] = {
  (float)(0.00390625            / 6.019333926786741),
  (float)(0.014328188175072987  / 6.019333926786741),
  (float)(0.04419417382415922   / 6.019333926786741),
  (float)(0.11462550540058389   / 6.019333926786741),
  (float)(0.25                  / 6.019333926786741),
  (float)(0.4585020216023356    / 6.019333926786741),
  (float)(0.7071067811865476    / 6.019333926786741),
  (float)(0.9170040432046712    / 6.019333926786741),
  (float)(1.0                  / 6.019333926786741),
  (float)(0.9170040432046712    / 6.019333926786741),
  (float)(0.7071067811865476    / 6.019333926786741),
  (float)(0.4585020216023356    / 6.019333926786741),
  (float)(0.25                  / 6.019333926786741),
  (float)(0.11462550540058389   / 6.019333926786741),
  (float)(0.04419417382415922   / 6.019333926786741),
  (float)(0.014328188175072987  / 6.019333926786741),
  (float)(0.00390625            / 6.019333926786741)
};

__device__ __forceinline__ unsigned bf16rne(float f) {
  unsigned u = __float_as_uint(f);
  return (u + 0x7fffu + ((u >> 16) & 1u)) >> 16;   // round-to-nearest-even
}

// K1: horizontal blur. hE[y][xi][b], hA[y][xi][b] (b innermost). Image reads coalesced.
__global__ void k_hblur(const float* __restrict__ img, const float* __restrict__ att,
                        float* __restrict__ hE, float* __restrict__ hA) {
  int xi = threadIdx.x;
  int y  = blockIdx.x;
  int b  = blockIdx.y;
  if (blockIdx.z == 0) {
    if (xi >= WE) return;
    const float* src = img + (b * IMG + y) * IMG;
    float acc = 0.f;
#pragma unroll
    for (int d = 0; d < 9; ++d) {
      int col = xi - 2 * RE + d;
      if (col >= 0 && col < IMG) acc = fmaf(KE[d], src[col], acc);
    }
    hE[(y * WE + xi) * NB + b] = acc;
  } else {
    if (xi >= WA) return;
    const float* src = att + (b * IMG + y) * IMG;
    float acc = 0.f;
#pragma unroll
    for (int d = 0; d < 17; ++d) {
      int col = xi - 2 * RA + d;
      if (col >= 0 && col < IMG) acc = fmaf(KA[d], src[col], acc);
    }
    hA[(y * WA + xi) * NB + b] = acc;
  }
}

// K2: vertical blur -> bf16 quad canvas over the live box [76,224)^2:
// P[y'][x'][b] = uint4{ E00|A00<<16, E01|A01<<16, E10|A10<<16, E11|A11<<16 }  (bf16 pairs)
// where (r,c) suffix = (y+r, x+c), A pre-scaled by 0.01. Whole 2x2 bilinear footprint
// of both images in ONE 16-B load for k_radon.
__global__ void k_canvas(const float* __restrict__ hE, const float* __restrict__ hA,
                         uint4* __restrict__ P) {
  int t  = threadIdx.x;
  int b  = t & 15;
  int xs = t >> 4;
  int xp = blockIdx.x * 16 + xs;        // x' in [0,148)
  int yp = blockIdx.y;                  // y' in [0,148)
  if (xp >= WB) return;

  float E00 = 0.f, E01 = 0.f, E10 = 0.f, E11 = 0.f;
  float A00 = 0.f, A01 = 0.f, A10 = 0.f, A11 = 0.f;
  {
    int xiE = xp - 6;                   // canvas x-82
    bool c0 = (xiE >= 0) & (xiE < WE);
    bool c1 = (xiE + 1 >= 0) & (xiE + 1 < WE);
#pragma unroll
    for (int d = 0; d < 10; ++d) {      // rows yp-14 .. yp-5 (covers y and y+1 blurs)
      int row = yp - 14 + d;
      if (row >= 0 && row < IMG) {
        const float* base = hE + (row * WE) * NB + b;
        float v0 = c0 ? base[xiE * NB] : 0.f;
        float v1 = c1 ? base[(xiE + 1) * NB] : 0.f;
        if (d < 9) { E00 = fmaf(KE[d], v0, E00); E01 = fmaf(KE[d], v1, E01); }
        if (d >= 1){ E10 = fmaf(KE[d-1], v0, E10); E11 = fmaf(KE[d-1], v1, E11); }
      }
    }
  }
  {
    int xiA = xp - 2;                   // canvas x-78
    bool c0 = (xiA >= 0) & (xiA < WA);
    bool c1 = (xiA + 1 >= 0) & (xiA + 1 < WA);
#pragma unroll
    for (int d = 0; d < 18; ++d) {      // rows yp-18 .. yp-1
      int row = yp - 18 + d;
      if (row >= 0 && row < IMG) {
        const float* base = hA + (row * WA) * NB + b;
        float v0 = c0 ? base[xiA * NB] : 0.f;
        float v1 = c1 ? base[(xiA + 1) * NB] : 0.f;
        if (d < 17) { A00 = fmaf(KA[d], v0, A00); A01 = fmaf(KA[d], v1, A01); }
        if (d >= 1) { A10 = fmaf(KA[d-1], v0, A10); A11 = fmaf(KA[d-1], v1, A11); }
      }
    }
  }
  uint4 q;
  q.x = bf16rne(E00) | (bf16rne(0.01f * A00) << 16);
  q.y = bf16rne(E01) | (bf16rne(0.01f * A01) << 16);
  q.z = bf16rne(E10) | (bf16rne(0.01f * A10) << 16);
  q.w = bf16rne(E11) | (bf16rne(0.01f * A11) << 16);
  P[(yp * WB + xp) * NB + b] = q;
}

// K3: radon for E and A together. Lanes: b = tid&15 (coalesced 256-B pixel lines),
// 4 bins/wave, ONE dwordx4 per sample (bf16 2x2 quad). 8x unrolled.
// Tail samples clamped to chord end 'hi' -> guaranteed-zero canvas -> exact 0.
__global__ void k_radon(const uint4* __restrict__ P, float* __restrict__ S) {
  int t = threadIdx.x;
  int b  = t & 15;
  int jj = t >> 4;
  int j  = blockIdx.x * 16 + jj;
  int a  = blockIdx.y;
  if (j >= NDET) return;
  float th = (float)a * (float)(3.14159265358979323846 / 299.0);
  float c = cosf(th), s = sinf(th);
  float xj = fmaf((float)j, (float)(2.0 / 299.0), -1.0f);
  // px(i) = pb + s*i ; py(i) = qb + c*i (unit step)
  float pb = fmaf(c,  xj, 1.0f) * 149.5f - 149.5f * s;
  float qb = fmaf(-s, xj, 1.0f) * 149.5f - 149.5f * c;
  const float L = 76.5f, H = 222.5f;
  float lo = 0.f, hi = 299.0f;
  if (s > 1e-6f) {                       // s >= 0 for theta in [0,180]
    float inv = 1.0f / s;
    lo = fmaxf(lo, (L - pb) * inv); hi = fminf(hi, (H - pb) * inv);
  } else if (pb < L || pb > H) { hi = -1.f; }
  if (fabsf(c) > 1e-6f) {
    float inv = 1.0f / c;
    float t0 = (L - qb) * inv, t1 = (H - qb) * inv;
    lo = fmaxf(lo, fminf(t0, t1)); hi = fminf(hi, fmaxf(t0, t1));
  } else if (qb < L || qb > H) { hi = -1.f; }
  int i0 = (int)ceilf(lo);
  int i1 = (int)floorf(hi);

  v2f acc = {0.f, 0.f};
  // byte offset: ((y0-76)*148 + (x0-76))*256 + b*16
  const char* Pc = (const char*)P;
  int boff = b * 16 - 76 * 149 * 256;

  for (int i = i0; i <= i1; i += 8) {
    uint4 q[8];
    float wx[8], wy[8];
#pragma unroll
    for (int u = 0; u < 8; ++u) {
      float fi = fminf((float)(i + u), hi);   // tail -> chord end -> zero canvas
      float px = fmaf(fi, s, pb);
      float py = fmaf(fi, c, qb);
      int x0 = (int)px, y0 = (int)py;         // px,py > 0 -> trunc == floor
      wx[u] = px - (float)x0;
      wy[u] = py - (float)y0;
      int off = (y0 * WB + x0) * 256 + boff;
      q[u] = *(const uint4*)(Pc + off);
    }
#pragma unroll
    for (int u = 0; u < 8; ++u) {
      v2f v00 = { __uint_as_float(q[u].x << 16), __uint_as_float(q[u].x & 0xffff0000u) };
      v2f v01 = { __uint_as_float(q[u].y << 16), __uint_as_float(q[u].y & 0xffff0000u) };
      v2f v10 = { __uint_as_float(q[u].z << 16), __uint_as_float(q[u].z & 0xffff0000u) };
      v2f v11 = { __uint_as_float(q[u].w << 16), __uint_as_float(q[u].w & 0xffff0000u) };
      v2f wx2 = {wx[u], wx[u]};
      v2f wy2 = {wy[u], wy[u]};
      v2f top = v00 + wx2 * (v01 - v00);
      v2f bot = v10 + wx2 * (v11 - v10);
      acc += top + wy2 * (bot - top);
    }
  }
  S[(a * NDET + j) * NB + b] = acc.x * expf(-2.0f * acc.y);  // VOXEL_MM = 2
}

// K4: per-angle 5-tap detector blur (reflect) + scale, write final [b][a][j].
__global__ void k_dblur(const float* __restrict__ S, const float* __restrict__ scale,
                        float* __restrict__ out) {
  int t = threadIdx.x;
  int b  = t & 15;
  int jj = t >> 4;
  int j  = blockIdx.x * 16 + jj;
  int a  = blockIdx.y;
  if (j >= NDET) return;
  float th = (float)a * (float)(3.14159265358979323846 / 299.0);
  float c = cosf(th), s = sinf(th);
  float u = fabsf(c) + fabsf(s);          // bw = 2u
  float u2 = u * u;
  float e1 = exp2f(-2.0f * u2);
  float e2 = exp2f(-8.0f * u2);
  float norm = 1.0f / (1.0f + 2.0f * (e1 + e2));
  float w2c = norm, w1c = e1 * norm, w0c = e2 * norm;
  const float* row = S + a * NDET * NB + b;
  float acc = 0.f;
#pragma unroll
  for (int tt = -2; tt <= 2; ++tt) {
    int jr = j + tt;
    if (jr < 0) jr = -jr;
    if (jr > 299) jr = 598 - jr;
    float w = (tt == 0) ? w2c : ((tt == 1 || tt == -1) ? w1c : w0c);
    acc = fmaf(w, row[jr * NB], acc);
  }
  out[(b * NANG + a) * NDET + j] = acc * scale[b];
}

extern "C" void kernel_launch(void* const* d_in, const int* in_sizes, int n_in,
                              void* d_out, int out_size, void* d_ws, size_t ws_size,
                              hipStream_t stream) {
  const float* img   = (const float*)d_in[0];
  const float* att   = (const float*)d_in[1];
  const float* scale = (const float*)d_in[2];
  float* out = (float*)d_out;
  float* ws  = (float*)d_ws;

  // ws layout (floats): P 148*148*16 uint4 (5.61 MB) | S 300*300*16 (5.76 MB) | hE | hA
  uint4*  P  = (uint4*)ws;
  float*  S  = ws + 1401856;
  float*  hE = ws + 2841856;
  float*  hA = ws + 3120384;

  k_hblur <<<dim3(IMG, NB, 2), 192, 0, stream>>>(img, att, hE, hA);
  k_canvas<<<dim3(10, WB),     256, 0, stream>>>(hE, hA, P);
  k_radon <<<dim3(19, NANG),   256, 0, stream>>>(P, S);
  k_dblur <<<dim3(19, NANG),   256, 0, stream>>>(S, scale, out);
}

// Round 6
// 169.201 us; speedup vs baseline: 1.2897x; 1.1117x over previous
//
#include <hip/hip_runtime.h>
#include <hip/hip_fp16.h>
#include <math.h>

#define NB   16     // batch
#define IMG  128    // input image side
#define NANG 300
#define NDET 300
#define RE   4      // emission blur radius  (sigma = 1/sqrt(ln2))
#define RA   8      // attenuation blur radius (sigma = 2/sqrt(ln2))
#define WE   (IMG + 2*RE)   // 136 ; hE col xi <-> canvas x = xi+82 ; E support x in [82,218)
#define WA   (IMG + 2*RA)   // 144 ; hA col xi <-> canvas x = xi+78 ; A support x in [78,222)
#define WB   148            // packed canvas box: x,y in [76,224)

typedef float    v2f __attribute__((ext_vector_type(2)));
typedef _Float16 v2h __attribute__((ext_vector_type(2)));

// Gaussian taps: sigma_img -> 2^(-d^2/2); sigma_att -> 2^(-d^2/8). f64 normalize, f32 cast.
__device__ __constant__ float KE[9] = {
  (float)(0.00390625            / 3.0104144100214136),
  (float)(0.04419417382415922   / 3.0104144100214136),
  (float)(0.25                  / 3.0104144100214136),
  (float)(0.7071067811865476    / 3.0104144100214136),
  (float)(1.0                   / 3.0104144100214136),
  (float)(0.7071067811865476    / 3.0104144100214136),
  (float)(0.25                  / 3.0104144100214136),
  (float)(0.04419417382415922   / 3.0104144100214136),
  (float)(0.00390625            / 3.0104144100214136)
};
__device__ __constant__ float KA[17] = {
  (float)(0.00390625            / 6.019333926786741),
  (float)(0.014328188175072987  / 6.019333926786741),
  (float)(0.04419417382415922   / 6.019333926786741),
  (float)(0.11462550540058389   / 6.019333926786741),
  (float)(0.25                  / 6.019333926786741),
  (float)(0.4585020216023356    / 6.019333926786741),
  (float)(0.7071067811865476    / 6.019333926786741),
  (float)(0.9170040432046712    / 6.019333926786741),
  (float)(1.0                   / 6.019333926786741),
  (float)(0.9170040432046712    / 6.019333926786741),
  (float)(0.7071067811865476    / 6.019333926786741),
  (float)(0.4585020216023356    / 6.019333926786741),
  (float)(0.25                  / 6.019333926786741),
  (float)(0.11462550540058389   / 6.019333926786741),
  (float)(0.04419417382415922   / 6.019333926786741),
  (float)(0.014328188175072987  / 6.019333926786741),
  (float)(0.00390625            / 6.019333926786741)
};

__device__ __forceinline__ unsigned h16(float f) {
  return (unsigned)__half_as_ushort(__float2half_rn(f));
}

__device__ __forceinline__ v2h pk16(float a, float b) {
  return __builtin_bit_cast(v2h, __builtin_amdgcn_cvt_pkrtz(a, b));
}

// K1: horizontal blur. hE[y][xi][b], hA[y][xi][b] (b innermost). Image reads coalesced.
__global__ void k_hblur(const float* __restrict__ img, const float* __restrict__ att,
                        float* __restrict__ hE, float* __restrict__ hA) {
  int xi = threadIdx.x;
  int y  = blockIdx.x;
  int b  = blockIdx.y;
  if (blockIdx.z == 0) {
    if (xi >= WE) return;
    const float* src = img + (b * IMG + y) * IMG;
    float acc = 0.f;
#pragma unroll
    for (int d = 0; d < 9; ++d) {
      int col = xi - 2 * RE + d;
      if (col >= 0 && col < IMG) acc = fmaf(KE[d], src[col], acc);
    }
    hE[(y * WE + xi) * NB + b] = acc;
  } else {
    if (xi >= WA) return;
    const float* src = att + (b * IMG + y) * IMG;
    float acc = 0.f;
#pragma unroll
    for (int d = 0; d < 17; ++d) {
      int col = xi - 2 * RA + d;
      if (col >= 0 && col < IMG) acc = fmaf(KA[d], src[col], acc);
    }
    hA[(y * WA + xi) * NB + b] = acc;
  }
}

// K2: vertical blur -> f16 quad canvas over the live box [76,224)^2:
// P[y'][x'][b] = uint4{ E00|E01<<16, E10|E11<<16, A00|A01<<16, A10|A11<<16 }  (f16 pairs)
// suffix (r,c) = (y+r, x+c); A pre-scaled by 0.01. Full 2x2 footprint of both images
// in ONE 16-B load, pre-paired for v_dot2_f32_f16.
__global__ void k_canvas(const float* __restrict__ hE, const float* __restrict__ hA,
                         uint4* __restrict__ P) {
  int t  = threadIdx.x;
  int b  = t & 15;
  int xs = t >> 4;
  int xp = blockIdx.x * 16 + xs;        // x' in [0,148)
  int yp = blockIdx.y;                  // y' in [0,148)
  if (xp >= WB) return;

  float E00 = 0.f, E01 = 0.f, E10 = 0.f, E11 = 0.f;
  float A00 = 0.f, A01 = 0.f, A10 = 0.f, A11 = 0.f;
  {
    int xiE = xp - 6;                   // canvas x-82
    bool c0 = (xiE >= 0) & (xiE < WE);
    bool c1 = (xiE + 1 >= 0) & (xiE + 1 < WE);
#pragma unroll
    for (int d = 0; d < 10; ++d) {      // rows yp-14 .. yp-5 (covers y and y+1 blurs)
      int row = yp - 14 + d;
      if (row >= 0 && row < IMG) {
        const float* base = hE + (row * WE) * NB + b;
        float v0 = c0 ? base[xiE * NB] : 0.f;
        float v1 = c1 ? base[(xiE + 1) * NB] : 0.f;
        if (d < 9) { E00 = fmaf(KE[d], v0, E00); E01 = fmaf(KE[d], v1, E01); }
        if (d >= 1){ E10 = fmaf(KE[d-1], v0, E10); E11 = fmaf(KE[d-1], v1, E11); }
      }
    }
  }
  {
    int xiA = xp - 2;                   // canvas x-78
    bool c0 = (xiA >= 0) & (xiA < WA);
    bool c1 = (xiA + 1 >= 0) & (xiA + 1 < WA);
#pragma unroll
    for (int d = 0; d < 18; ++d) {      // rows yp-18 .. yp-1
      int row = yp - 18 + d;
      if (row >= 0 && row < IMG) {
        const float* base = hA + (row * WA) * NB + b;
        float v0 = c0 ? base[xiA * NB] : 0.f;
        float v1 = c1 ? base[(xiA + 1) * NB] : 0.f;
        if (d < 17) { A00 = fmaf(KA[d], v0, A00); A01 = fmaf(KA[d], v1, A01); }
        if (d >= 1) { A10 = fmaf(KA[d-1], v0, A10); A11 = fmaf(KA[d-1], v1, A11); }
      }
    }
  }
  uint4 q;
  q.x = h16(E00) | (h16(E01) << 16);
  q.y = h16(E10) | (h16(E11) << 16);
  q.z = h16(0.01f * A00) | (h16(0.01f * A01) << 16);
  q.w = h16(0.01f * A10) | (h16(0.01f * A11) << 16);
  P[(yp * WB + xp) * NB + b] = q;
}

// K3: radon for E and A together. Lanes: b = tid&15 (coalesced 256-B pixel lines),
// 4 bins/wave, ONE dwordx4 per sample, bilinear via 4x v_dot2_f32_f16.
// Tail samples clamped to chord end 'hi' -> guaranteed-zero canvas -> exact 0.
__global__ void k_radon(const uint4* __restrict__ P, float* __restrict__ S) {
  int t = threadIdx.x;
  int b  = t & 15;
  int jj = t >> 4;
  int j  = blockIdx.x * 16 + jj;
  int a  = blockIdx.y;
  if (j >= NDET) return;
  float th = (float)a * (float)(3.14159265358979323846 / 299.0);
  float c = cosf(th), s = sinf(th);
  float xj = fmaf((float)j, (float)(2.0 / 299.0), -1.0f);
  // px(i) = pb + s*i ; py(i) = qb + c*i (unit step)
  float pb = fmaf(c,  xj, 1.0f) * 149.5f - 149.5f * s;
  float qb = fmaf(-s, xj, 1.0f) * 149.5f - 149.5f * c;
  const float L = 76.5f, H = 222.5f;
  float lo = 0.f, hi = 299.0f;
  if (s > 1e-6f) {                       // s >= 0 for theta in [0,180]
    float inv = 1.0f / s;
    lo = fmaxf(lo, (L - pb) * inv); hi = fminf(hi, (H - pb) * inv);
  } else if (pb < L || pb > H) { hi = -1.f; }
  if (fabsf(c) > 1e-6f) {
    float inv = 1.0f / c;
    float t0 = (L - qb) * inv, t1 = (H - qb) * inv;
    lo = fmaxf(lo, fminf(t0, t1)); hi = fminf(hi, fmaxf(t0, t1));
  } else if (qb < L || qb > H) { hi = -1.f; }
  int i0 = (int)ceilf(lo);
  int i1 = (int)floorf(hi);

  float sE0 = 0.f, sE1 = 0.f, sA0 = 0.f, sA1 = 0.f;
  // byte offset: ((y0-76)*148 + (x0-76))*256 + b*16
  const char* Pc = (const char*)P;
  int boff = b * 16 - 76 * 149 * 256;

  for (int i = i0; i <= i1; i += 8) {
    uint4 q[8];
    v2h w0[8], w1[8];
#pragma unroll
    for (int u = 0; u < 8; ++u) {
      float fi = fminf((float)(i + u), hi);   // tail -> chord end -> zero canvas
      float px = fmaf(fi, s, pb);
      float py = fmaf(fi, c, qb);
      float x0f = floorf(px), y0f = floorf(py);
      float wx = px - x0f, wy = py - y0f;
      int idx = (int)fmaf(y0f, (float)WB, x0f);
      int off = idx * 256 + boff;
      q[u] = *(const uint4*)(Pc + off);
      float omx = 1.0f - wx, omy = 1.0f - wy;
      w0[u] = pk16(omy * omx, omy * wx);  // (w00, w01)
      w1[u] = pk16(wy * omx,  wy * wx);   // (w10, w11)
    }
#pragma unroll
    for (int u = 0; u < 8; ++u) {
      v2h e0 = __builtin_bit_cast(v2h, q[u].x);
      v2h e1 = __builtin_bit_cast(v2h, q[u].y);
      v2h a0 = __builtin_bit_cast(v2h, q[u].z);
      v2h a1 = __builtin_bit_cast(v2h, q[u].w);
      sE0 = __builtin_amdgcn_fdot2(e0, w0[u], sE0, false);
      sE1 = __builtin_amdgcn_fdot2(e1, w1[u], sE1, false);
      sA0 = __builtin_amdgcn_fdot2(a0, w0[u], sA0, false);
      sA1 = __builtin_amdgcn_fdot2(a1, w1[u], sA1, false);
    }
  }
  float sumE = sE0 + sE1, sumA = sA0 + sA1;
  S[(a * NB + b) * NDET + j] = sumE * expf(-2.0f * sumA);  // VOXEL_MM = 2; layout [a][b][j]
}

// K4: per-angle 5-tap detector blur (reflect) + scale. S is [a][b][j] -> fully
// coalesced reads along j; out [b][a][j] coalesced writes.
__global__ void k_dblur(const float* __restrict__ S, const float* __restrict__ scale,
                        float* __restrict__ out) {
  int j = threadIdx.x;
  int a = blockIdx.x;
  int b = blockIdx.y;
  if (j >= NDET) return;
  float th = (float)a * (float)(3.14159265358979323846 / 299.0);
  float c = cosf(th), s = sinf(th);
  float u = fabsf(c) + fabsf(s);          // bw = 2u
  float u2 = u * u;
  float e1 = exp2f(-2.0f * u2);
  float e2 = exp2f(-8.0f * u2);
  float norm = 1.0f / (1.0f + 2.0f * (e1 + e2));
  float w2c = norm, w1c = e1 * norm, w0c = e2 * norm;
  const float* row = S + (a * NB + b) * NDET;
  float acc = 0.f;
#pragma unroll
  for (int tt = -2; tt <= 2; ++tt) {
    int jr = j + tt;
    if (jr < 0) jr = -jr;
    if (jr > 299) jr = 598 - jr;
    float w = (tt == 0) ? w2c : ((tt == 1 || tt == -1) ? w1c : w0c);
    acc = fmaf(w, row[jr], acc);
  }
  out[(b * NANG + a) * NDET + j] = acc * scale[b];
}

extern "C" void kernel_launch(void* const* d_in, const int* in_sizes, int n_in,
                              void* d_out, int out_size, void* d_ws, size_t ws_size,
                              hipStream_t stream) {
  const float* img   = (const float*)d_in[0];
  const float* att   = (const float*)d_in[1];
  const float* scale = (const float*)d_in[2];
  float* out = (float*)d_out;
  float* ws  = (float*)d_ws;

  // ws layout (floats): P 148*148*16 uint4 (5.61 MB) | S 300*300*16 (5.76 MB) | hE | hA
  uint4*  P  = (uint4*)ws;
  float*  S  = ws + 1401856;
  float*  hE = ws + 2841856;
  float*  hA = ws + 3120384;

  k_hblur <<<dim3(IMG, NB, 2), 192, 0, stream>>>(img, att, hE, hA);
  k_canvas<<<dim3(10, WB),     256, 0, stream>>>(hE, hA, P);
  k_radon <<<dim3(19, NANG),   256, 0, stream>>>(P, S);
  k_dblur <<<dim3(NANG, NB),   320, 0, stream>>>(S, scale, out);
}